// Round 3
// baseline (2966.271 us; speedup 1.0000x reference)
//
#include <hip/hip_runtime.h>

#define NN 50000
#define EE 800000
#define RR 3
#define HH 128

typedef __attribute__((ext_vector_type(8))) short short8;
typedef __attribute__((ext_vector_type(4))) float f32x4;
typedef unsigned short u16;
typedef unsigned int u32;

__device__ __forceinline__ float b2f(u16 u){
  unsigned v = ((unsigned)u) << 16;
  return __builtin_bit_cast(float, v);
}
__device__ __forceinline__ u16 f2bu(float f){
  unsigned u = __builtin_bit_cast(unsigned, f);
  u += 0x7fffu + ((u >> 16) & 1u);
  return (u16)(u >> 16);
}
__device__ __forceinline__ float coefhi(u32 u){
  return __builtin_bit_cast(float, u & 0xffff0000u);
}

__global__ __launch_bounds__(256) void zero_k(int* p, int n){
  int i = blockIdx.x * 256 + threadIdx.x;
  if (i < n) p[i] = 0;
}

__global__ __launch_bounds__(256) void count_deg(const int* __restrict__ src, const int* __restrict__ dst,
                                                 int* __restrict__ dout, int* __restrict__ din){
  int i = blockIdx.x * 256 + threadIdx.x;
  if (i >= RR * EE) return;
  int r = i / EE;
  atomicAdd(&dout[r * NN + src[i]], 1);
  atomicAdd(&din[r * NN + dst[i]], 1);
}

// int degree -> float 1/sqrt(max(deg,1)) IN PLACE (run after scan_rows)
__global__ __launch_bounds__(256) void norms_k(int* dio, int n){
  int i = blockIdx.x * 256 + threadIdx.x;
  if (i >= n) return;
  int v = dio[i]; if (v < 1) v = 1;
  ((float*)dio)[i] = rsqrtf((float)v);
}

// one block per relation: exclusive scan of in-degrees -> row_ptr, cursor
__global__ __launch_bounds__(256) void scan_rows(const int* __restrict__ cnt, int* __restrict__ row_ptr,
                                                 int* __restrict__ cursor){
  int r = blockIdx.x;
  const int* c = cnt + r * NN;
  int* rp = row_ptr + r * (NN + 1);
  int* cur = cursor + r * NN;
  __shared__ int buf[2][256];
  __shared__ int sbase;
  int t = threadIdx.x;
  if (t == 0){ rp[0] = 0; sbase = 0; }
  __syncthreads();
  for (int chunk = 0; chunk < NN; chunk += 256){
    int i = chunk + t;
    int v = (i < NN) ? c[i] : 0;
    int sel = 0;
    buf[0][t] = v;
    __syncthreads();
    for (int off = 1; off < 256; off <<= 1){
      int nv = buf[sel][t] + ((t >= off) ? buf[sel][t - off] : 0);
      buf[sel ^ 1][t] = nv;
      sel ^= 1;
      __syncthreads();
    }
    int incl = buf[sel][t];
    int base = sbase;
    if (i < NN){ rp[i + 1] = base + incl; cur[i] = base + incl - v; }
    __syncthreads();
    if (t == 255) sbase = base + incl;
    __syncthreads();
  }
}

// pack (src node id | bf16(norm_out[src]) << 16) into CSR-by-dst slots
__global__ __launch_bounds__(256) void scatter_k(const int* __restrict__ src, const int* __restrict__ dst,
                                                 int* __restrict__ cursor, const float* __restrict__ nout,
                                                 u32* __restrict__ ecol){
  int i = blockIdx.x * 256 + threadIdx.x;
  if (i >= RR * EE) return;
  int r = i / EE;
  int s = src[i], d = dst[i];
  int p = atomicAdd(&cursor[r * NN + d], 1);
  u16 c = f2bu(nout[r * NN + s]);
  ecol[(size_t)r * EE + p] = (u32)s | ((u32)c << 16);
}

// fp32 -> bf16 conversion, 4 elements/thread
__global__ __launch_bounds__(256) void cvt_bf16(const float* __restrict__ in, u16* __restrict__ out, int n4){
  int i = blockIdx.x * 256 + threadIdx.x;
  if (i >= n4) return;
  float4 v = ((const float4*)in)[i];
  ushort4 o; o.x = f2bu(v.x); o.y = f2bu(v.y); o.z = f2bu(v.z); o.w = f2bu(v.w);
  ((ushort4*)out)[i] = o;
}

// pack fp32 B[k][n] -> bf16 Bp[(k>>3)][n][k&7] per batch matrix
__global__ __launch_bounds__(256) void pack_bf(const float* __restrict__ B, u16* __restrict__ Bp,
                                               int K, int nc, int total){
  int i = blockIdx.x * 256 + threadIdx.x;
  if (i >= total) return;
  int per = K * nc;
  int b = i / per, rem = i % per;
  int k = rem / nc, n = rem % nc;
  Bp[b * per + ((k >> 3) * nc + n) * 8 + (k & 7)] = f2bu(B[i]);
}

// Fused layer: per block = 64 nodes. For each relation: gather neighborhood
// rows of bf16 activations into LDS tile (norm_out folded per edge, norm_in
// applied after), MFMA 64x128 @ W_r[128,128] accumulating across relations;
// then h -> LDS -> fc GEMM.
// MODE 0: fc[128,128] + bias + relu + BN -> bf16 act_out[N,128]
// MODE 1: fc[128,512] + bias -> fp32 out[N,512]
template<int MODE>
__global__ __launch_bounds__(256) void fused_layer(
    const u16* __restrict__ xin, const u32* __restrict__ ecol,
    const int* __restrict__ row_ptr, const float* __restrict__ nin,
    const u16* __restrict__ Wc, const float* __restrict__ bc,
    const u16* __restrict__ Wf, const float* __restrict__ bfc,
    const float* __restrict__ g, const float* __restrict__ be,
    const float* __restrict__ mu, const float* __restrict__ va,
    u16* __restrict__ out_bf, float* __restrict__ out_f)
{
  __shared__ u16 tile[64][136];   // row stride 272B = 17*16B: 16B-aligned frags + bank spread
  int tid = threadIdx.x, wave = tid >> 6, lane = tid & 63;
  int q = lane >> 4, l15 = lane & 15;
  int nb = blockIdx.x * 64;
  f32x4 zf = {0.f, 0.f, 0.f, 0.f};
  f32x4 acc[8];
#pragma unroll
  for (int ct = 0; ct < 8; ++ct) acc[ct] = zf;

  for (int r = 0; r < RR; ++r){
    const u32* ec = ecol + (size_t)r * EE;
    const int* rp = row_ptr + r * (NN + 1);
    // gather: this wave owns tile rows wave*16 .. wave*16+15
    for (int t = 0; t < 16; ++t){
      int node = nb + wave * 16 + t;
      float a0 = 0.f, a1 = 0.f, sc = 0.f;
      int e0 = 0, e1 = 0;
      if (node < NN){ e0 = rp[node]; e1 = rp[node + 1]; sc = nin[r * NN + node]; }
      for (int e = e0; e < e1; ++e){
        u32 u = ec[e];
        int s = (int)(u & 0xffffu);
        float c = coefhi(u);
        ushort2 v = *(const ushort2*)(xin + (size_t)s * HH + lane * 2);
        a0 += c * b2f(v.x); a1 += c * b2f(v.y);
      }
      ushort2 o; o.x = f2bu(sc * a0); o.y = f2bu(sc * a1);
      *(ushort2*)&tile[wave * 16 + t][lane * 2] = o;
    }
    __syncthreads();
    // MFMA this relation's K=128 slice of the conv weight (batch r at offset r*128*128)
    const short8* bp = (const short8*)(Wc + (size_t)r * HH * HH);
#pragma unroll
    for (int kb = 0; kb < 4; ++kb){
      short8 a = *(const short8*)&tile[wave * 16 + l15][kb * 32 + q * 8];
#pragma unroll
      for (int ct = 0; ct < 8; ++ct){
        short8 b = bp[(kb * 4 + q) * HH + ct * 16 + l15];
        acc[ct] = __builtin_amdgcn_mfma_f32_16x16x32_bf16(a, b, acc[ct], 0, 0, 0);
      }
    }
    __syncthreads();
  }

  // conv bias (sum over 3 relations), h -> LDS (own rows only)
#pragma unroll
  for (int ct = 0; ct < 8; ++ct){
    int col = ct * 16 + l15;
    float badd = bc[col] + bc[HH + col] + bc[2 * HH + col];
#pragma unroll
    for (int i = 0; i < 4; ++i)
      tile[wave * 16 + q * 4 + i][col] = f2bu(acc[ct][i] + badd);
  }
  __syncthreads();

  if (MODE == 0){
    f32x4 a2[8];
#pragma unroll
    for (int ct = 0; ct < 8; ++ct) a2[ct] = zf;
    const short8* bp = (const short8*)Wf;
#pragma unroll
    for (int kb = 0; kb < 4; ++kb){
      short8 a = *(const short8*)&tile[wave * 16 + l15][kb * 32 + q * 8];
#pragma unroll
      for (int ct = 0; ct < 8; ++ct){
        short8 b = bp[(kb * 4 + q) * HH + ct * 16 + l15];
        a2[ct] = __builtin_amdgcn_mfma_f32_16x16x32_bf16(a, b, a2[ct], 0, 0, 0);
      }
    }
#pragma unroll
    for (int ct = 0; ct < 8; ++ct){
      int col = ct * 16 + l15;
      float bb = bfc[col];
      float s0 = g[col] * rsqrtf(va[col] + 1e-5f);
      float m0 = mu[col], b0 = be[col];
#pragma unroll
      for (int i = 0; i < 4; ++i){
        int node = nb + wave * 16 + q * 4 + i;
        if (node < NN){
          float v = a2[ct][i] + bb;
          v = fmaxf(v, 0.f);
          v = (v - m0) * s0 + b0;
          out_bf[(size_t)node * HH + col] = f2bu(v);
        }
      }
    }
  } else {
    // wave handles output cols [wave*128, wave*128+128), all 64 rows
    f32x4 a2[4][8];
#pragma unroll
    for (int rt = 0; rt < 4; ++rt)
#pragma unroll
      for (int ct = 0; ct < 8; ++ct) a2[rt][ct] = zf;
    const short8* bp = (const short8*)Wf;
#pragma unroll
    for (int kb = 0; kb < 4; ++kb){
      int cbase = (kb * 4 + q) * 512 + wave * 128;
#pragma unroll
      for (int rt = 0; rt < 4; ++rt){
        short8 a = *(const short8*)&tile[rt * 16 + l15][kb * 32 + q * 8];
#pragma unroll
        for (int ct = 0; ct < 8; ++ct){
          short8 b = bp[cbase + ct * 16 + l15];
          a2[rt][ct] = __builtin_amdgcn_mfma_f32_16x16x32_bf16(a, b, a2[rt][ct], 0, 0, 0);
        }
      }
    }
#pragma unroll
    for (int rt = 0; rt < 4; ++rt)
#pragma unroll
    for (int ct = 0; ct < 8; ++ct){
      int col = wave * 128 + ct * 16 + l15;
      float bb = bfc[col];
#pragma unroll
      for (int i = 0; i < 4; ++i){
        int node = nb + rt * 16 + q * 4 + i;
        if (node < NN) out_f[(size_t)node * 512 + col] = a2[rt][ct][i] + bb;
      }
    }
  }
}

extern "C" void kernel_launch(void* const* d_in, const int* in_sizes, int n_in,
                              void* d_out, int out_size, void* d_ws, size_t ws_size,
                              hipStream_t stream){
  const float* x_in  = (const float*)d_in[0];
  const int* esrc    = (const int*)d_in[1];
  const int* edst    = (const int*)d_in[2];
  const float* convW = (const float*)d_in[3];
  const float* convB = (const float*)d_in[4];
  const float* fcW   = (const float*)d_in[5];
  const float* fcB   = (const float*)d_in[6];
  const float* fcWl  = (const float*)d_in[7];
  const float* fcBl  = (const float*)d_in[8];
  const float* bng   = (const float*)d_in[9];
  const float* bnb   = (const float*)d_in[10];
  const float* bnm   = (const float*)d_in[11];
  const float* bnv   = (const float*)d_in[12];

  char* w = (char*)d_ws;
  size_t off = 0;
  auto alloc = [&](size_t bytes) -> char* {
    char* p = w + off;
    off += (bytes + 255) & ~(size_t)255;
    return p;
  };
  int* degs    = (int*)alloc((size_t)2 * RR * NN * 4);   // deg_out | deg_in (-> norms in place)
  int* row_ptr = (int*)alloc((size_t)RR * (NN + 1) * 4);
  int* cursor  = (int*)alloc((size_t)RR * NN * 4);
  u32* ecol    = (u32*)alloc((size_t)RR * EE * 4);
  u16* xb      = (u16*)alloc((size_t)NN * HH * 2);   // bf16 copy of layer input
  u16* act1    = (u16*)alloc((size_t)NN * HH * 2);
  u16* act2    = (u16*)alloc((size_t)NN * HH * 2);
  u16* convWp  = (u16*)alloc((size_t)3 * 384 * 128 * 2);
  u16* fcWp    = (u16*)alloc((size_t)2 * 128 * 128 * 2);
  u16* fcWlp   = (u16*)alloc((size_t)128 * 512 * 2);
  // total ~51 MB

  int* deg_out = degs;
  int* deg_in  = degs + (size_t)RR * NN;
  float* nrm_out = (float*)deg_out;
  float* nrm_in  = (float*)deg_in;

  const int TPB = 256;
  zero_k<<<(2 * RR * NN + TPB - 1) / TPB, TPB, 0, stream>>>(degs, 2 * RR * NN);
  count_deg<<<(RR * EE + TPB - 1) / TPB, TPB, 0, stream>>>(esrc, edst, deg_out, deg_in);
  scan_rows<<<RR, TPB, 0, stream>>>(deg_in, row_ptr, cursor);      // reads int deg_in
  norms_k<<<(2 * RR * NN + TPB - 1) / TPB, TPB, 0, stream>>>(degs, 2 * RR * NN); // in-place int->float
  scatter_k<<<(RR * EE + TPB - 1) / TPB, TPB, 0, stream>>>(esrc, edst, cursor, nrm_out, ecol);
  cvt_bf16<<<(NN * HH / 4 + TPB - 1) / TPB, TPB, 0, stream>>>(x_in, xb, NN * HH / 4);
  pack_bf<<<(3 * 384 * 128 + TPB - 1) / TPB, TPB, 0, stream>>>(convW, convWp, 384, 128, 3 * 384 * 128);
  pack_bf<<<(2 * 128 * 128 + TPB - 1) / TPB, TPB, 0, stream>>>(fcW, fcWp, 128, 128, 2 * 128 * 128);
  pack_bf<<<(128 * 512 + TPB - 1) / TPB, TPB, 0, stream>>>(fcWl, fcWlp, 128, 512, 128 * 512);

  int gx = (NN + 63) / 64;
  fused_layer<0><<<gx, TPB, 0, stream>>>(xb, ecol, row_ptr, nrm_in,
      convWp + (size_t)0 * 384 * 128, convB + 0 * 384,
      fcWp + (size_t)0 * 128 * 128, fcB + 0 * 128,
      bng + 0 * 128, bnb + 0 * 128, bnm + 0 * 128, bnv + 0 * 128, act1, nullptr);
  fused_layer<0><<<gx, TPB, 0, stream>>>(act1, ecol, row_ptr, nrm_in,
      convWp + (size_t)1 * 384 * 128, convB + 1 * 384,
      fcWp + (size_t)1 * 128 * 128, fcB + 1 * 128,
      bng + 1 * 128, bnb + 1 * 128, bnm + 1 * 128, bnv + 1 * 128, act2, nullptr);
  fused_layer<1><<<gx, TPB, 0, stream>>>(act2, ecol, row_ptr, nrm_in,
      convWp + (size_t)2 * 384 * 128, convB + 2 * 384,
      fcWlp, fcBl,
      nullptr, nullptr, nullptr, nullptr, nullptr, (float*)d_out);
}

// Round 4
// 1549.925 us; speedup vs baseline: 1.9138x; 1.9138x over previous
//
#include <hip/hip_runtime.h>

#define NN 50000
#define EE 800000
#define RR 3
#define HH 128
#define SCAN_B 2048
#define GB 25   // ceil(NN / SCAN_B)

typedef __attribute__((ext_vector_type(8))) short short8;
typedef __attribute__((ext_vector_type(4))) float f32x4;
typedef unsigned short u16;
typedef unsigned int u32;

__device__ __forceinline__ float b2f(u16 u){
  unsigned v = ((unsigned)u) << 16;
  return __builtin_bit_cast(float, v);
}
__device__ __forceinline__ u16 f2bu(float f){
  unsigned u = __builtin_bit_cast(unsigned, f);
  u += 0x7fffu + ((u >> 16) & 1u);
  return (u16)(u >> 16);
}
__device__ __forceinline__ float coefhi(u32 u){
  return __builtin_bit_cast(float, u & 0xffff0000u);
}

__global__ __launch_bounds__(256) void zero_k(int* p, int n){
  int i = blockIdx.x * 256 + threadIdx.x;
  if (i < n) p[i] = 0;
}

__global__ __launch_bounds__(256) void count_deg(const int* __restrict__ src, const int* __restrict__ dst,
                                                 int* __restrict__ dout, int* __restrict__ din){
  int i = blockIdx.x * 256 + threadIdx.x;
  if (i >= RR * EE) return;
  int r = i / EE;
  atomicAdd(&dout[r * NN + src[i]], 1);
  atomicAdd(&din[r * NN + dst[i]], 1);
}

// int degree -> float 1/sqrt(max(deg,1)) IN PLACE (after scan has consumed ints)
__global__ __launch_bounds__(256) void norms_k(int* dio, int n){
  int i = blockIdx.x * 256 + threadIdx.x;
  if (i >= n) return;
  int v = dio[i]; if (v < 1) v = 1;
  ((float*)dio)[i] = rsqrtf((float)v);
}

// ---- parallel scan of in-degrees -> row_ptr, cursor ----
__global__ __launch_bounds__(256) void scan_bsum(const int* __restrict__ cnt, int* __restrict__ bsum){
  int r = blockIdx.y, b = blockIdx.x, t = threadIdx.x;
  const int* c = cnt + r * NN;
  int i0 = b * SCAN_B + t * 8;
  int s = 0;
#pragma unroll
  for (int j = 0; j < 8; ++j){ int i = i0 + j; s += (i < NN) ? c[i] : 0; }
  __shared__ int ls[256];
  ls[t] = s; __syncthreads();
  for (int off = 128; off > 0; off >>= 1){
    if (t < off) ls[t] += ls[t + off];
    __syncthreads();
  }
  if (t == 0) bsum[r * GB + b] = ls[0];
}

__global__ void scan_boff(int* bsum){
  if (threadIdx.x == 0){
    for (int r = 0; r < RR; ++r){
      int acc = 0;
      for (int b = 0; b < GB; ++b){ int v = bsum[r * GB + b]; bsum[r * GB + b] = acc; acc += v; }
    }
  }
}

__global__ __launch_bounds__(256) void scan_write(const int* __restrict__ cnt, const int* __restrict__ bsum,
                                                  int* __restrict__ row_ptr, int* __restrict__ cursor){
  int r = blockIdx.y, b = blockIdx.x, t = threadIdx.x;
  const int* c = cnt + r * NN;
  int* rp = row_ptr + r * (NN + 1);
  int* cur = cursor + r * NN;
  int i0 = b * SCAN_B + t * 8;
  int v[8]; int s = 0;
#pragma unroll
  for (int j = 0; j < 8; ++j){ int i = i0 + j; v[j] = (i < NN) ? c[i] : 0; s += v[j]; }
  __shared__ int ls[2][256];
  int sel = 0;
  ls[0][t] = s; __syncthreads();
  for (int off = 1; off < 256; off <<= 1){
    int nv = ls[sel][t] + ((t >= off) ? ls[sel][t - off] : 0);
    ls[sel ^ 1][t] = nv;
    sel ^= 1;
    __syncthreads();
  }
  int excl = ls[sel][t] - s;
  int run = bsum[r * GB + b] + excl;
  if (t == 0 && b == 0) rp[0] = 0;
#pragma unroll
  for (int j = 0; j < 8; ++j){
    int i = i0 + j;
    if (i < NN){ rp[i + 1] = run + v[j]; cur[i] = run; run += v[j]; }
  }
}

// pack (src node id | bf16(norm_out[src]) << 16) into CSR-by-dst slots
__global__ __launch_bounds__(256) void scatter_k(const int* __restrict__ src, const int* __restrict__ dst,
                                                 int* __restrict__ cursor, const float* __restrict__ nout,
                                                 u32* __restrict__ ecol){
  int i = blockIdx.x * 256 + threadIdx.x;
  if (i >= RR * EE) return;
  int r = i / EE;
  int s = src[i], d = dst[i];
  int p = atomicAdd(&cursor[r * NN + d], 1);
  u16 c = f2bu(nout[r * NN + s]);
  ecol[(size_t)r * EE + p] = (u32)s | ((u32)c << 16);
}

__global__ __launch_bounds__(256) void cvt_bf16(const float* __restrict__ in, u16* __restrict__ out, int n4){
  int i = blockIdx.x * 256 + threadIdx.x;
  if (i >= n4) return;
  float4 v = ((const float4*)in)[i];
  ushort4 o; o.x = f2bu(v.x); o.y = f2bu(v.y); o.z = f2bu(v.z); o.w = f2bu(v.w);
  ((ushort4*)out)[i] = o;
}

// pack fp32 B[k][n] -> bf16 Bp[(k>>3)][n][k&7] per batch matrix
__global__ __launch_bounds__(256) void pack_bf(const float* __restrict__ B, u16* __restrict__ Bp,
                                               int K, int nc, int total){
  int i = blockIdx.x * 256 + threadIdx.x;
  if (i >= total) return;
  int per = K * nc;
  int b = i / per, rem = i % per;
  int k = rem / nc, n = rem % nc;
  Bp[b * per + ((k >> 3) * nc + n) * 8 + (k & 7)] = f2bu(B[i]);
}

// Fused layer. MODE 0: conv + fc[128,128] + bias + relu + BN -> bf16 [N,128]
//              MODE 1: conv + fc[128,512] + bias -> fp32 out [N,512]
template<int MODE>
__global__ __launch_bounds__(256) void fused_layer(
    const u16* __restrict__ xin, const u32* __restrict__ ecol,
    const int* __restrict__ row_ptr, const float* __restrict__ nin,
    const u16* __restrict__ Wc, const float* __restrict__ bc,
    const u16* __restrict__ Wf, const float* __restrict__ bfc,
    const float* __restrict__ g, const float* __restrict__ be,
    const float* __restrict__ mu, const float* __restrict__ va,
    u16* __restrict__ out_bf, float* __restrict__ out_f)
{
  __shared__ u16 tile[64][136];
  int tid = threadIdx.x, wave = tid >> 6, lane = tid & 63;
  int q = lane >> 4, l15 = lane & 15;
  int nb = blockIdx.x * 64;
  f32x4 zf = {0.f, 0.f, 0.f, 0.f};
  f32x4 acc[8];
#pragma unroll
  for (int ct = 0; ct < 8; ++ct) acc[ct] = zf;

  for (int r = 0; r < RR; ++r){
    const u32* ec = ecol + (size_t)r * EE;
    const int* rp = row_ptr + r * (NN + 1);
    for (int t = 0; t < 16; ++t){
      int node = nb + wave * 16 + t;
      float sc = 0.f;
      int e0 = 0, e1 = 0;
      if (node < NN){ e0 = rp[node]; e1 = rp[node + 1]; sc = nin[r * NN + node]; }
      float a0 = 0.f, a1 = 0.f, p0 = 0.f, p1 = 0.f;
      float c0 = 0.f, c1 = 0.f, d0 = 0.f, d1 = 0.f;
      int e = e0;
      // 4-way unrolled: 4 independent 256B row-loads in flight per wave
      for (; e + 4 <= e1; e += 4){
        u32 u0 = ec[e], u1 = ec[e + 1], u2 = ec[e + 2], u3 = ec[e + 3];
        ushort2 v0 = *(const ushort2*)(xin + (size_t)(u0 & 0xffffu) * HH + lane * 2);
        ushort2 v1 = *(const ushort2*)(xin + (size_t)(u1 & 0xffffu) * HH + lane * 2);
        ushort2 v2 = *(const ushort2*)(xin + (size_t)(u2 & 0xffffu) * HH + lane * 2);
        ushort2 v3 = *(const ushort2*)(xin + (size_t)(u3 & 0xffffu) * HH + lane * 2);
        float f0 = coefhi(u0), f1 = coefhi(u1), f2 = coefhi(u2), f3 = coefhi(u3);
        a0 += f0 * b2f(v0.x); a1 += f0 * b2f(v0.y);
        p0 += f1 * b2f(v1.x); p1 += f1 * b2f(v1.y);
        c0 += f2 * b2f(v2.x); c1 += f2 * b2f(v2.y);
        d0 += f3 * b2f(v3.x); d1 += f3 * b2f(v3.y);
      }
      for (; e < e1; ++e){
        u32 u = ec[e];
        ushort2 v = *(const ushort2*)(xin + (size_t)(u & 0xffffu) * HH + lane * 2);
        float f = coefhi(u);
        a0 += f * b2f(v.x); a1 += f * b2f(v.y);
      }
      float s0 = sc * ((a0 + p0) + (c0 + d0));
      float s1 = sc * ((a1 + p1) + (c1 + d1));
      ushort2 o; o.x = f2bu(s0); o.y = f2bu(s1);
      *(ushort2*)&tile[wave * 16 + t][lane * 2] = o;
    }
    __syncthreads();
    const short8* bp = (const short8*)(Wc + (size_t)r * HH * HH);
#pragma unroll
    for (int kb = 0; kb < 4; ++kb){
      short8 a = *(const short8*)&tile[wave * 16 + l15][kb * 32 + q * 8];
#pragma unroll
      for (int ct = 0; ct < 8; ++ct){
        short8 b = bp[(kb * 4 + q) * HH + ct * 16 + l15];
        acc[ct] = __builtin_amdgcn_mfma_f32_16x16x32_bf16(a, b, acc[ct], 0, 0, 0);
      }
    }
    __syncthreads();
  }

  // conv bias (summed over relations), h -> LDS
#pragma unroll
  for (int ct = 0; ct < 8; ++ct){
    int col = ct * 16 + l15;
    float badd = bc[col] + bc[HH + col] + bc[2 * HH + col];
#pragma unroll
    for (int i = 0; i < 4; ++i)
      tile[wave * 16 + q * 4 + i][col] = f2bu(acc[ct][i] + badd);
  }
  __syncthreads();

  if (MODE == 0){
    f32x4 a2[8];
#pragma unroll
    for (int ct = 0; ct < 8; ++ct) a2[ct] = zf;
    const short8* bp = (const short8*)Wf;
#pragma unroll
    for (int kb = 0; kb < 4; ++kb){
      short8 a = *(const short8*)&tile[wave * 16 + l15][kb * 32 + q * 8];
#pragma unroll
      for (int ct = 0; ct < 8; ++ct){
        short8 b = bp[(kb * 4 + q) * HH + ct * 16 + l15];
        a2[ct] = __builtin_amdgcn_mfma_f32_16x16x32_bf16(a, b, a2[ct], 0, 0, 0);
      }
    }
#pragma unroll
    for (int ct = 0; ct < 8; ++ct){
      int col = ct * 16 + l15;
      float bb = bfc[col];
      float s0 = g[col] * rsqrtf(va[col] + 1e-5f);
      float m0 = mu[col], b0 = be[col];
#pragma unroll
      for (int i = 0; i < 4; ++i){
        int node = nb + wave * 16 + q * 4 + i;
        if (node < NN){
          float v = a2[ct][i] + bb;
          v = fmaxf(v, 0.f);
          v = (v - m0) * s0 + b0;
          out_bf[(size_t)node * HH + col] = f2bu(v);
        }
      }
    }
  } else {
    f32x4 a2[4][8];
#pragma unroll
    for (int rt = 0; rt < 4; ++rt)
#pragma unroll
      for (int ct = 0; ct < 8; ++ct) a2[rt][ct] = zf;
    const short8* bp = (const short8*)Wf;
#pragma unroll
    for (int kb = 0; kb < 4; ++kb){
      int cbase = (kb * 4 + q) * 512 + wave * 128;
#pragma unroll
      for (int rt = 0; rt < 4; ++rt){
        short8 a = *(const short8*)&tile[rt * 16 + l15][kb * 32 + q * 8];
#pragma unroll
        for (int ct = 0; ct < 8; ++ct){
          short8 b = bp[cbase + ct * 16 + l15];
          a2[rt][ct] = __builtin_amdgcn_mfma_f32_16x16x32_bf16(a, b, a2[rt][ct], 0, 0, 0);
        }
      }
    }
#pragma unroll
    for (int rt = 0; rt < 4; ++rt)
#pragma unroll
    for (int ct = 0; ct < 8; ++ct){
      int col = wave * 128 + ct * 16 + l15;
      float bb = bfc[col];
#pragma unroll
      for (int i = 0; i < 4; ++i){
        int node = nb + rt * 16 + q * 4 + i;
        if (node < NN) out_f[(size_t)node * 512 + col] = a2[rt][ct][i] + bb;
      }
    }
  }
}

extern "C" void kernel_launch(void* const* d_in, const int* in_sizes, int n_in,
                              void* d_out, int out_size, void* d_ws, size_t ws_size,
                              hipStream_t stream){
  const float* x_in  = (const float*)d_in[0];
  const int* esrc    = (const int*)d_in[1];
  const int* edst    = (const int*)d_in[2];
  const float* convW = (const float*)d_in[3];
  const float* convB = (const float*)d_in[4];
  const float* fcW   = (const float*)d_in[5];
  const float* fcB   = (const float*)d_in[6];
  const float* fcWl  = (const float*)d_in[7];
  const float* fcBl  = (const float*)d_in[8];
  const float* bng   = (const float*)d_in[9];
  const float* bnb   = (const float*)d_in[10];
  const float* bnm   = (const float*)d_in[11];
  const float* bnv   = (const float*)d_in[12];

  char* w = (char*)d_ws;
  size_t off = 0;
  auto alloc = [&](size_t bytes) -> char* {
    char* p = w + off;
    off += (bytes + 255) & ~(size_t)255;
    return p;
  };
  int* degs    = (int*)alloc((size_t)2 * RR * NN * 4);
  int* row_ptr = (int*)alloc((size_t)RR * (NN + 1) * 4);
  int* cursor  = (int*)alloc((size_t)RR * NN * 4);
  int* bsum    = (int*)alloc((size_t)RR * GB * 4);
  u32* ecol    = (u32*)alloc((size_t)RR * EE * 4);
  u16* xb      = (u16*)alloc((size_t)NN * HH * 2);
  u16* act1    = (u16*)alloc((size_t)NN * HH * 2);
  u16* act2    = (u16*)alloc((size_t)NN * HH * 2);
  u16* convWp  = (u16*)alloc((size_t)3 * 384 * 128 * 2);
  u16* fcWp    = (u16*)alloc((size_t)2 * 128 * 128 * 2);
  u16* fcWlp   = (u16*)alloc((size_t)128 * 512 * 2);

  int* deg_out = degs;
  int* deg_in  = degs + (size_t)RR * NN;
  float* nrm_out = (float*)deg_out;
  float* nrm_in  = (float*)deg_in;

  const int TPB = 256;
  zero_k<<<(2 * RR * NN + TPB - 1) / TPB, TPB, 0, stream>>>(degs, 2 * RR * NN);
  count_deg<<<(RR * EE + TPB - 1) / TPB, TPB, 0, stream>>>(esrc, edst, deg_out, deg_in);
  scan_bsum<<<dim3(GB, RR), TPB, 0, stream>>>(deg_in, bsum);
  scan_boff<<<1, 64, 0, stream>>>(bsum);
  scan_write<<<dim3(GB, RR), TPB, 0, stream>>>(deg_in, bsum, row_ptr, cursor);
  norms_k<<<(2 * RR * NN + TPB - 1) / TPB, TPB, 0, stream>>>(degs, 2 * RR * NN);
  scatter_k<<<(RR * EE + TPB - 1) / TPB, TPB, 0, stream>>>(esrc, edst, cursor, nrm_out, ecol);
  cvt_bf16<<<(NN * HH / 4 + TPB - 1) / TPB, TPB, 0, stream>>>(x_in, xb, NN * HH / 4);
  pack_bf<<<(3 * 384 * 128 + TPB - 1) / TPB, TPB, 0, stream>>>(convW, convWp, 384, 128, 3 * 384 * 128);
  pack_bf<<<(2 * 128 * 128 + TPB - 1) / TPB, TPB, 0, stream>>>(fcW, fcWp, 128, 128, 2 * 128 * 128);
  pack_bf<<<(128 * 512 + TPB - 1) / TPB, TPB, 0, stream>>>(fcWl, fcWlp, 128, 512, 128 * 512);

  int gx = (NN + 63) / 64;
  fused_layer<0><<<gx, TPB, 0, stream>>>(xb, ecol, row_ptr, nrm_in,
      convWp + (size_t)0 * 384 * 128, convB + 0 * 384,
      fcWp + (size_t)0 * 128 * 128, fcB + 0 * 128,
      bng + 0 * 128, bnb + 0 * 128, bnm + 0 * 128, bnv + 0 * 128, act1, nullptr);
  fused_layer<0><<<gx, TPB, 0, stream>>>(act1, ecol, row_ptr, nrm_in,
      convWp + (size_t)1 * 384 * 128, convB + 1 * 384,
      fcWp + (size_t)1 * 128 * 128, fcB + 1 * 128,
      bng + 1 * 128, bnb + 1 * 128, bnm + 1 * 128, bnv + 1 * 128, act2, nullptr);
  fused_layer<1><<<gx, TPB, 0, stream>>>(act2, ecol, row_ptr, nrm_in,
      convWp + (size_t)2 * 384 * 128, convB + 2 * 384,
      fcWlp, fcBl,
      nullptr, nullptr, nullptr, nullptr, nullptr, (float*)d_out);
}

// Round 5
// 1243.426 us; speedup vs baseline: 2.3856x; 1.2465x over previous
//
#include <hip/hip_runtime.h>

#define NN 50000
#define EE 800000
#define RR 3
#define HH 128
#define SCAN_B 2048
#define GB 25   // ceil(NN / SCAN_B)

typedef __attribute__((ext_vector_type(8))) short short8;
typedef __attribute__((ext_vector_type(4))) float f32x4;
typedef unsigned short u16;
typedef unsigned int u32;

__device__ __forceinline__ float b2f(u16 u){
  unsigned v = ((unsigned)u) << 16;
  return __builtin_bit_cast(float, v);
}
__device__ __forceinline__ u16 f2bu(float f){
  unsigned u = __builtin_bit_cast(unsigned, f);
  u += 0x7fffu + ((u >> 16) & 1u);
  return (u16)(u >> 16);
}
__device__ __forceinline__ float coefhi(u32 u){
  return __builtin_bit_cast(float, u & 0xffff0000u);
}

__global__ __launch_bounds__(256) void zero_k(int* p, int n){
  int i = blockIdx.x * 256 + threadIdx.x;
  if (i < n) p[i] = 0;
}

__global__ __launch_bounds__(256) void count_deg(const int* __restrict__ src, const int* __restrict__ dst,
                                                 int* __restrict__ dout, int* __restrict__ din){
  int i = blockIdx.x * 256 + threadIdx.x;
  if (i >= RR * EE) return;
  int r = i / EE;
  atomicAdd(&dout[r * NN + src[i]], 1);
  atomicAdd(&din[r * NN + dst[i]], 1);
}

__global__ __launch_bounds__(256) void norms_k(int* dio, int n){
  int i = blockIdx.x * 256 + threadIdx.x;
  if (i >= n) return;
  int v = dio[i]; if (v < 1) v = 1;
  ((float*)dio)[i] = rsqrtf((float)v);
}

// ---- parallel scan of in-degrees -> row_ptr, cursor ----
__global__ __launch_bounds__(256) void scan_bsum(const int* __restrict__ cnt, int* __restrict__ bsum){
  int r = blockIdx.y, b = blockIdx.x, t = threadIdx.x;
  const int* c = cnt + r * NN;
  int i0 = b * SCAN_B + t * 8;
  int s = 0;
#pragma unroll
  for (int j = 0; j < 8; ++j){ int i = i0 + j; s += (i < NN) ? c[i] : 0; }
  __shared__ int ls[256];
  ls[t] = s; __syncthreads();
  for (int off = 128; off > 0; off >>= 1){
    if (t < off) ls[t] += ls[t + off];
    __syncthreads();
  }
  if (t == 0) bsum[r * GB + b] = ls[0];
}

__global__ void scan_boff(int* bsum){
  if (threadIdx.x == 0){
    for (int r = 0; r < RR; ++r){
      int acc = 0;
      for (int b = 0; b < GB; ++b){ int v = bsum[r * GB + b]; bsum[r * GB + b] = acc; acc += v; }
    }
  }
}

__global__ __launch_bounds__(256) void scan_write(const int* __restrict__ cnt, const int* __restrict__ bsum,
                                                  int* __restrict__ row_ptr, int* __restrict__ cursor){
  int r = blockIdx.y, b = blockIdx.x, t = threadIdx.x;
  const int* c = cnt + r * NN;
  int* rp = row_ptr + r * (NN + 1);
  int* cur = cursor + r * NN;
  int i0 = b * SCAN_B + t * 8;
  int v[8]; int s = 0;
#pragma unroll
  for (int j = 0; j < 8; ++j){ int i = i0 + j; v[j] = (i < NN) ? c[i] : 0; s += v[j]; }
  __shared__ int ls[2][256];
  int sel = 0;
  ls[0][t] = s; __syncthreads();
  for (int off = 1; off < 256; off <<= 1){
    int nv = ls[sel][t] + ((t >= off) ? ls[sel][t - off] : 0);
    ls[sel ^ 1][t] = nv;
    sel ^= 1;
    __syncthreads();
  }
  int excl = ls[sel][t] - s;
  int run = bsum[r * GB + b] + excl;
  if (t == 0 && b == 0) rp[0] = 0;
#pragma unroll
  for (int j = 0; j < 8; ++j){
    int i = i0 + j;
    if (i < NN){ rp[i + 1] = run + v[j]; cur[i] = run; run += v[j]; }
  }
}

__global__ __launch_bounds__(256) void scatter_k(const int* __restrict__ src, const int* __restrict__ dst,
                                                 int* __restrict__ cursor, const float* __restrict__ nout,
                                                 u32* __restrict__ ecol){
  int i = blockIdx.x * 256 + threadIdx.x;
  if (i >= RR * EE) return;
  int r = i / EE;
  int s = src[i], d = dst[i];
  int p = atomicAdd(&cursor[r * NN + d], 1);
  u16 c = f2bu(nout[r * NN + s]);
  ecol[(size_t)r * EE + p] = (u32)s | ((u32)c << 16);
}

__global__ __launch_bounds__(256) void cvt_bf16(const float* __restrict__ in, u16* __restrict__ out, int n4){
  int i = blockIdx.x * 256 + threadIdx.x;
  if (i >= n4) return;
  float4 v = ((const float4*)in)[i];
  ushort4 o; o.x = f2bu(v.x); o.y = f2bu(v.y); o.z = f2bu(v.z); o.w = f2bu(v.w);
  ((ushort4*)out)[i] = o;
}

__global__ __launch_bounds__(256) void pack_bf(const float* __restrict__ B, u16* __restrict__ Bp,
                                               int K, int nc, int total){
  int i = blockIdx.x * 256 + threadIdx.x;
  if (i >= total) return;
  int per = K * nc;
  int b = i / per, rem = i % per;
  int k = rem / nc, n = rem % nc;
  Bp[b * per + ((k >> 3) * nc + n) * 8 + (k & 7)] = f2bu(B[i]);
}

// Fused layer. Gather: half-wave (32 lanes) per dst row, ushort4/lane, 4-edge
// unroll -> 8 independent 256B row loads in flight per wave.
// MODE 0: conv + fc[128,128] + bias + relu + BN -> bf16 [N,128]
// MODE 1: conv + fc[128,512] + bias -> fp32 out [N,512]
template<int MODE>
__global__ __launch_bounds__(256) void fused_layer(
    const u16* __restrict__ xin, const u32* __restrict__ ecol,
    const int* __restrict__ row_ptr, const float* __restrict__ nin,
    const u16* __restrict__ Wc, const float* __restrict__ bc,
    const u16* __restrict__ Wf, const float* __restrict__ bfc,
    const float* __restrict__ g, const float* __restrict__ be,
    const float* __restrict__ mu, const float* __restrict__ va,
    u16* __restrict__ out_bf, float* __restrict__ out_f)
{
  __shared__ u16 tile[64][136];
  int tid = threadIdx.x, wave = tid >> 6, lane = tid & 63;
  int q = lane >> 4, l15 = lane & 15;
  int pr = lane >> 5;        // half index: row offset
  int hl = lane & 31;        // lane within half
  int nb = blockIdx.x * 64;
  f32x4 zf = {0.f, 0.f, 0.f, 0.f};
  f32x4 acc[8];
#pragma unroll
  for (int ct = 0; ct < 8; ++ct) acc[ct] = zf;

  for (int r = 0; r < RR; ++r){
    const u32* ec = ecol + (size_t)r * EE;
    const int* rp = row_ptr + r * (NN + 1);
    for (int t = 0; t < 16; t += 2){
      int node = nb + wave * 16 + t + pr;
      float sc = 0.f;
      int e0 = 0, e1 = 0;
      if (node < NN){ e0 = rp[node]; e1 = rp[node + 1]; sc = nin[r * NN + node]; }
      float ax[4], bx[4], cx[4], dx[4];
#pragma unroll
      for (int j = 0; j < 4; ++j){ ax[j] = 0.f; bx[j] = 0.f; cx[j] = 0.f; dx[j] = 0.f; }
      int e = e0;
      for (; e + 4 <= e1; e += 4){
        u32 u0 = ec[e], u1 = ec[e + 1], u2 = ec[e + 2], u3 = ec[e + 3];
        ushort4 v0 = *(const ushort4*)(xin + (size_t)(u0 & 0xffffu) * HH + hl * 4);
        ushort4 v1 = *(const ushort4*)(xin + (size_t)(u1 & 0xffffu) * HH + hl * 4);
        ushort4 v2 = *(const ushort4*)(xin + (size_t)(u2 & 0xffffu) * HH + hl * 4);
        ushort4 v3 = *(const ushort4*)(xin + (size_t)(u3 & 0xffffu) * HH + hl * 4);
        float f0 = coefhi(u0), f1 = coefhi(u1), f2 = coefhi(u2), f3 = coefhi(u3);
        ax[0] += f0 * b2f(v0.x); ax[1] += f0 * b2f(v0.y); ax[2] += f0 * b2f(v0.z); ax[3] += f0 * b2f(v0.w);
        bx[0] += f1 * b2f(v1.x); bx[1] += f1 * b2f(v1.y); bx[2] += f1 * b2f(v1.z); bx[3] += f1 * b2f(v1.w);
        cx[0] += f2 * b2f(v2.x); cx[1] += f2 * b2f(v2.y); cx[2] += f2 * b2f(v2.z); cx[3] += f2 * b2f(v2.w);
        dx[0] += f3 * b2f(v3.x); dx[1] += f3 * b2f(v3.y); dx[2] += f3 * b2f(v3.z); dx[3] += f3 * b2f(v3.w);
      }
      for (; e < e1; ++e){
        u32 u = ec[e];
        ushort4 v = *(const ushort4*)(xin + (size_t)(u & 0xffffu) * HH + hl * 4);
        float f = coefhi(u);
        ax[0] += f * b2f(v.x); ax[1] += f * b2f(v.y); ax[2] += f * b2f(v.z); ax[3] += f * b2f(v.w);
      }
      ushort4 o;
      o.x = f2bu(sc * ((ax[0] + bx[0]) + (cx[0] + dx[0])));
      o.y = f2bu(sc * ((ax[1] + bx[1]) + (cx[1] + dx[1])));
      o.z = f2bu(sc * ((ax[2] + bx[2]) + (cx[2] + dx[2])));
      o.w = f2bu(sc * ((ax[3] + bx[3]) + (cx[3] + dx[3])));
      *(ushort4*)&tile[wave * 16 + t + pr][hl * 4] = o;
    }
    __syncthreads();
    const short8* bp = (const short8*)(Wc + (size_t)r * HH * HH);
#pragma unroll
    for (int kb = 0; kb < 4; ++kb){
      short8 a = *(const short8*)&tile[wave * 16 + l15][kb * 32 + q * 8];
#pragma unroll
      for (int ct = 0; ct < 8; ++ct){
        short8 b = bp[(kb * 4 + q) * HH + ct * 16 + l15];
        acc[ct] = __builtin_amdgcn_mfma_f32_16x16x32_bf16(a, b, acc[ct], 0, 0, 0);
      }
    }
    __syncthreads();
  }

  // conv bias (summed over relations), h -> LDS
#pragma unroll
  for (int ct = 0; ct < 8; ++ct){
    int col = ct * 16 + l15;
    float badd = bc[col] + bc[HH + col] + bc[2 * HH + col];
#pragma unroll
    for (int i = 0; i < 4; ++i)
      tile[wave * 16 + q * 4 + i][col] = f2bu(acc[ct][i] + badd);
  }
  __syncthreads();

  if (MODE == 0){
    f32x4 a2[8];
#pragma unroll
    for (int ct = 0; ct < 8; ++ct) a2[ct] = zf;
    const short8* bp = (const short8*)Wf;
#pragma unroll
    for (int kb = 0; kb < 4; ++kb){
      short8 a = *(const short8*)&tile[wave * 16 + l15][kb * 32 + q * 8];
#pragma unroll
      for (int ct = 0; ct < 8; ++ct){
        short8 b = bp[(kb * 4 + q) * HH + ct * 16 + l15];
        a2[ct] = __builtin_amdgcn_mfma_f32_16x16x32_bf16(a, b, a2[ct], 0, 0, 0);
      }
    }
#pragma unroll
    for (int ct = 0; ct < 8; ++ct){
      int col = ct * 16 + l15;
      float bb = bfc[col];
      float s0 = g[col] * rsqrtf(va[col] + 1e-5f);
      float m0 = mu[col], b0 = be[col];
#pragma unroll
      for (int i = 0; i < 4; ++i){
        int node = nb + wave * 16 + q * 4 + i;
        if (node < NN){
          float v = a2[ct][i] + bb;
          v = fmaxf(v, 0.f);
          v = (v - m0) * s0 + b0;
          out_bf[(size_t)node * HH + col] = f2bu(v);
        }
      }
    }
  } else {
    f32x4 a2[4][8];
#pragma unroll
    for (int rt = 0; rt < 4; ++rt)
#pragma unroll
      for (int ct = 0; ct < 8; ++ct) a2[rt][ct] = zf;
    const short8* bp = (const short8*)Wf;
#pragma unroll
    for (int kb = 0; kb < 4; ++kb){
      int cbase = (kb * 4 + q) * 512 + wave * 128;
#pragma unroll
      for (int rt = 0; rt < 4; ++rt){
        short8 a = *(const short8*)&tile[rt * 16 + l15][kb * 32 + q * 8];
#pragma unroll
        for (int ct = 0; ct < 8; ++ct){
          short8 b = bp[cbase + ct * 16 + l15];
          a2[rt][ct] = __builtin_amdgcn_mfma_f32_16x16x32_bf16(a, b, a2[rt][ct], 0, 0, 0);
        }
      }
    }
#pragma unroll
    for (int rt = 0; rt < 4; ++rt)
#pragma unroll
    for (int ct = 0; ct < 8; ++ct){
      int col = wave * 128 + ct * 16 + l15;
      float bb = bfc[col];
#pragma unroll
      for (int i = 0; i < 4; ++i){
        int node = nb + rt * 16 + q * 4 + i;
        if (node < NN) out_f[(size_t)node * 512 + col] = a2[rt][ct][i] + bb;
      }
    }
  }
}

extern "C" void kernel_launch(void* const* d_in, const int* in_sizes, int n_in,
                              void* d_out, int out_size, void* d_ws, size_t ws_size,
                              hipStream_t stream){
  const float* x_in  = (const float*)d_in[0];
  const int* esrc    = (const int*)d_in[1];
  const int* edst    = (const int*)d_in[2];
  const float* convW = (const float*)d_in[3];
  const float* convB = (const float*)d_in[4];
  const float* fcW   = (const float*)d_in[5];
  const float* fcB   = (const float*)d_in[6];
  const float* fcWl  = (const float*)d_in[7];
  const float* fcBl  = (const float*)d_in[8];
  const float* bng   = (const float*)d_in[9];
  const float* bnb   = (const float*)d_in[10];
  const float* bnm   = (const float*)d_in[11];
  const float* bnv   = (const float*)d_in[12];

  char* w = (char*)d_ws;
  size_t off = 0;
  auto alloc = [&](size_t bytes) -> char* {
    char* p = w + off;
    off += (bytes + 255) & ~(size_t)255;
    return p;
  };
  int* degs    = (int*)alloc((size_t)2 * RR * NN * 4);
  int* row_ptr = (int*)alloc((size_t)RR * (NN + 1) * 4);
  int* cursor  = (int*)alloc((size_t)RR * NN * 4);
  int* bsum    = (int*)alloc((size_t)RR * GB * 4);
  u32* ecol    = (u32*)alloc((size_t)RR * EE * 4);
  u16* xb      = (u16*)alloc((size_t)NN * HH * 2);
  u16* act1    = (u16*)alloc((size_t)NN * HH * 2);
  u16* act2    = (u16*)alloc((size_t)NN * HH * 2);
  u16* convWp  = (u16*)alloc((size_t)3 * 384 * 128 * 2);
  u16* fcWp    = (u16*)alloc((size_t)2 * 128 * 128 * 2);
  u16* fcWlp   = (u16*)alloc((size_t)128 * 512 * 2);

  int* deg_out = degs;
  int* deg_in  = degs + (size_t)RR * NN;
  float* nrm_out = (float*)deg_out;
  float* nrm_in  = (float*)deg_in;

  const int TPB = 256;
  zero_k<<<(2 * RR * NN + TPB - 1) / TPB, TPB, 0, stream>>>(degs, 2 * RR * NN);
  count_deg<<<(RR * EE + TPB - 1) / TPB, TPB, 0, stream>>>(esrc, edst, deg_out, deg_in);
  scan_bsum<<<dim3(GB, RR), TPB, 0, stream>>>(deg_in, bsum);
  scan_boff<<<1, 64, 0, stream>>>(bsum);
  scan_write<<<dim3(GB, RR), TPB, 0, stream>>>(deg_in, bsum, row_ptr, cursor);
  norms_k<<<(2 * RR * NN + TPB - 1) / TPB, TPB, 0, stream>>>(degs, 2 * RR * NN);
  scatter_k<<<(RR * EE + TPB - 1) / TPB, TPB, 0, stream>>>(esrc, edst, cursor, nrm_out, ecol);
  cvt_bf16<<<(NN * HH / 4 + TPB - 1) / TPB, TPB, 0, stream>>>(x_in, xb, NN * HH / 4);
  pack_bf<<<(3 * 384 * 128 + TPB - 1) / TPB, TPB, 0, stream>>>(convW, convWp, 384, 128, 3 * 384 * 128);
  pack_bf<<<(2 * 128 * 128 + TPB - 1) / TPB, TPB, 0, stream>>>(fcW, fcWp, 128, 128, 2 * 128 * 128);
  pack_bf<<<(128 * 512 + TPB - 1) / TPB, TPB, 0, stream>>>(fcWl, fcWlp, 128, 512, 128 * 512);

  int gx = (NN + 63) / 64;
  fused_layer<0><<<gx, TPB, 0, stream>>>(xb, ecol, row_ptr, nrm_in,
      convWp + (size_t)0 * 384 * 128, convB + 0 * 384,
      fcWp + (size_t)0 * 128 * 128, fcB + 0 * 128,
      bng + 0 * 128, bnb + 0 * 128, bnm + 0 * 128, bnv + 0 * 128, act1, nullptr);
  fused_layer<0><<<gx, TPB, 0, stream>>>(act1, ecol, row_ptr, nrm_in,
      convWp + (size_t)1 * 384 * 128, convB + 1 * 384,
      fcWp + (size_t)1 * 128 * 128, fcB + 1 * 128,
      bng + 1 * 128, bnb + 1 * 128, bnm + 1 * 128, bnv + 1 * 128, act2, nullptr);
  fused_layer<1><<<gx, TPB, 0, stream>>>(act2, ecol, row_ptr, nrm_in,
      convWp + (size_t)2 * 384 * 128, convB + 2 * 384,
      fcWlp, fcBl,
      nullptr, nullptr, nullptr, nullptr, nullptr, (float*)d_out);
}